// Round 10
// baseline (385.652 us; speedup 1.0000x reference)
//
#include <hip/hip_runtime.h>
#include <hip/hip_bf16.h>

// SAGE reranker, round 10: latency-optimized gathers.
// R9 diag: fp8 halved gather FETCH (91->46MB) but time ~flat (51->49us) ->
// latency-bound, not BW-bound. Fix: (1) block's adj window (contiguous, bucket-
// sorted) staged coalesced into LDS -> per-edge index is a ds_read not a 500cyc
// global load; (2) 4 nodes per wave INTERLEAVED -> 64 row-gathers in flight
// (was 16, serial per node). Applied to both combine0 and combine1_head.

#define DIN 256
#define DH 128
#define NPB 512
#define NBMAX 128
#define EPB 2048
#define JL (EPB/256)
#define CAP 12288
#define SLOTS 16384

typedef __attribute__((ext_vector_type(8))) short short8;
typedef __attribute__((ext_vector_type(4))) float float4v;
typedef __attribute__((ext_vector_type(2))) float float2v;

__device__ inline ushort f2b(float f){
  unsigned u = __float_as_uint(f);
  u = (u + 0x7fffu + ((u >> 16) & 1u)) >> 16;   // round-nearest-even
  return (ushort)u;
}
__device__ inline float blo(unsigned v){ return __uint_as_float(v << 16); }
__device__ inline float bhi(unsigned v){ return __uint_as_float(v & 0xffff0000u); }
__device__ inline short8 pack8(float4 f0, float4 f1){
  short8 v;
  v[0]=(short)f2b(f0.x); v[1]=(short)f2b(f0.y); v[2]=(short)f2b(f0.z); v[3]=(short)f2b(f0.w);
  v[4]=(short)f2b(f1.x); v[5]=(short)f2b(f1.y); v[6]=(short)f2b(f1.z); v[7]=(short)f2b(f1.w);
  return v;
}
__device__ inline void glds16(const ushort* g, ushort* l){
  __builtin_amdgcn_global_load_lds((const __attribute__((address_space(1))) void*)g,
                                   (__attribute__((address_space(3))) void*)l, 16, 0, 0);
}
__device__ inline unsigned char enc8(float v){
  return (unsigned char)(__builtin_amdgcn_cvt_pk_fp8_f32(v, v, 0, false) & 0xFF);
}
__device__ inline float2v dec8(unsigned u){
  return __builtin_amdgcn_cvt_pk_f32_fp8((int)u, false);
}

// ================= L1: fused front: [partition | convert-x | weight prep] =================
__global__ __launch_bounds__(256) void fused_front(
    const float* __restrict__ x, int N, ushort* __restrict__ xb, int nstripe,
    const float* __restrict__ Wp, const float* __restrict__ Wl0, const float* __restrict__ Wr0,
    const float* __restrict__ Wl1, const float* __restrict__ Wr1, const float* __restrict__ W1,
    ushort* __restrict__ Wpf, ushort* __restrict__ Wl0f, ushort* __restrict__ Wr0f,
    ushort* __restrict__ Wl1f, ushort* __restrict__ Wr1f, ushort* __restrict__ W1f,
    const int* __restrict__ src, const int* __restrict__ dst, int E, int NB,
    int* __restrict__ bucketCnt, int* __restrict__ pairS, int* __restrict__ pairD,
    int nPart, int nConv)
{
  __shared__ int hist[NBMAX], lbase[NBMAX], gbase[NBMAX], lcur[NBMAX], sc[NBMAX];
  __shared__ int ls[EPB], ld[EPB];
  int bid = blockIdx.x;
  int t = threadIdx.x;

  if (bid < nPart){
    int base = bid * EPB;
    int cntE = E - base; if (cntE > EPB) cntE = EPB;
    for (int i=t;i<NB;i+=256) hist[i]=0;
    __syncthreads();
    int myS[JL], myD[JL];
    #pragma unroll
    for (int j=0;j<JL;j++){
      int e = base + j*256 + t;
      if (e < E){ myS[j]=src[e]; myD[j]=dst[e]; atomicAdd(&hist[myD[j]>>9],1); }
      else myD[j] = -1;
    }
    __syncthreads();
    if (t < NBMAX) sc[t] = (t < NB)? hist[t] : 0;
    __syncthreads();
    for (int st=1; st<NBMAX; st<<=1){
      int v = 0;
      if (t < NBMAX && t >= st) v = sc[t-st];
      __syncthreads();
      if (t < NBMAX) sc[t] += v;
      __syncthreads();
    }
    if (t < NB){
      int excl = (t>0)? sc[t-1] : 0;
      lbase[t] = excl; lcur[t] = excl;
      gbase[t] = atomicAdd(&bucketCnt[t], hist[t]);
    }
    __syncthreads();
    #pragma unroll
    for (int j=0;j<JL;j++){
      if (myD[j] >= 0){
        int b = myD[j] >> 9;
        int p = atomicAdd(&lcur[b], 1);
        ls[p] = myS[j]; ld[p] = myD[j];
      }
    }
    __syncthreads();
    for (int i=t;i<cntE;i+=256){
      int d = ld[i];
      int b = d >> 9;
      int p = gbase[b] + (i - lbase[b]);
      if (p < SLOTS){
        pairS[(size_t)b*SLOTS + p] = ls[i];
        pairD[(size_t)b*SLOTS + p] = d;
      }
    }
  } else if (bid < nPart + nConv){
    int gi = (bid - nPart)*256 + t;
    if (gi < nstripe*512){
      int L = gi & 63, ks = (gi>>6)&7, s = gi>>9;
      int row = s*16 + (L&15);
      int k = ks*32 + (L>>4)*8;
      short8 v;
      if (row < N){
        const float* p = x + (size_t)row*DIN + k;
        v = pack8(*(const float4*)p, *(const float4*)(p+4));
      } else {
        #pragma unroll
        for (int j=0;j<8;j++) v[j]=0;
      }
      *(short8*)(xb + (size_t)gi*8) = v;
    }
  } else {
    int gi = (bid - nPart - nConv)*256 + t;
    if (gi < 17408){
      const float* sw; ushort* dw; int cols, b0;
      if      (gi <  4096){ sw=Wp;  dw=Wpf;  cols=128; b0=0; }
      else if (gi <  8192){ sw=Wl0; dw=Wl0f; cols=128; b0=4096; }
      else if (gi < 12288){ sw=Wr0; dw=Wr0f; cols=128; b0=8192; }
      else if (gi < 14336){ sw=Wl1; dw=Wl1f; cols=128; b0=12288; }
      else if (gi < 16384){ sw=Wr1; dw=Wr1f; cols=128; b0=14336; }
      else                { sw=W1;  dw=W1f;  cols=64;  b0=16384; }
      int i = gi - b0;
      int ln = i & 63, g = i >> 6;
      int ntq = cols >> 4;
      int nt = g % ntq, ks = g / ntq;
      int col = nt*16 + (ln & 15);
      int k0 = ks*32 + (ln >> 4)*8;
      short8 v;
      #pragma unroll
      for (int j=0;j<8;j++) v[j] = (short)f2b(sw[(size_t)(k0+j)*cols + col]);
      *(short8*)(dw + (size_t)i*8) = v;
    }
  }
}

// ================= L2: [GEMM0 wres | bucket_csr]; mat1 (xl0) output is fp8 =================
__global__ __launch_bounds__(256) void gemm0_csr(
    const ushort* __restrict__ xb, int N, int nstripe, int ngemm,
    const ushort* __restrict__ Wpf, const ushort* __restrict__ Wl0f, const ushort* __restrict__ Wr0f,
    const float* __restrict__ bp,
    ushort* __restrict__ xp, unsigned char* __restrict__ q8, ushort* __restrict__ xr0,
    const int* __restrict__ bucketCnt, const int* __restrict__ pairS, const int* __restrict__ pairD,
    int* __restrict__ off, int* __restrict__ deg, int* __restrict__ adj)
{
  __shared__ __align__(16) ushort smem[32768];
  int bid = blockIdx.x, t = threadIdx.x;

  if (bid < ngemm){
    int mat = bid % 3, b = bid / 3;
    int nblk = ngemm / 3;
    const ushort* Wf = (mat==0)? Wpf : (mat==1)? Wl0f : Wr0f;
    int w = t>>6, lane = t&63, lq = lane&15, quad = lane>>4;
    #pragma unroll
    for (int j=0;j<16;j++){
      int g = w + j*4;
      glds16(Wf + (size_t)g*512 + lane*8, smem + g*512);
    }
    __syncthreads();
    float bias[8];
    #pragma unroll
    for (int nt=0;nt<8;nt++) bias[nt] = (mat==0)? bp[nt*16 + lq] : 0.f;
    int nchunk = (nstripe + 3) >> 2;
    for (int c = b; c < nchunk; c += nblk){
      int stripe = c*4 + w;
      int row0 = stripe*16;
      if (row0 >= N) continue;
      short8 av[8];
      #pragma unroll
      for (int ks=0;ks<8;ks++)
        av[ks] = *(const short8*)(xb + ((size_t)stripe*8 + ks)*512 + lane*8);
      float4v acc[8];
      #pragma unroll
      for (int nt=0;nt<8;nt++)
        #pragma unroll
        for (int r=0;r<4;r++) acc[nt][r] = 0.f;
      #pragma unroll
      for (int ks=0;ks<8;ks++){
        #pragma unroll
        for (int nt=0;nt<8;nt++){
          short8 bf = *(const short8*)(smem + (size_t)((ks*8 + nt)*64 + lane)*8);
          acc[nt] = __builtin_amdgcn_mfma_f32_16x16x32_bf16(av[ks], bf, acc[nt], 0,0,0);
        }
      }
      if (mat == 1){
        #pragma unroll
        for (int nt=0;nt<8;nt++)
          #pragma unroll
          for (int r=0;r<4;r++){
            int row = row0 + quad*4 + r;
            if (row < N) q8[(size_t)row*128 + nt*16 + lq] = enc8(acc[nt][r]);
          }
      } else {
        ushort* Y = (mat==0)? xp : xr0;
        #pragma unroll
        for (int nt=0;nt<8;nt++)
          #pragma unroll
          for (int r=0;r<4;r++){
            int row = row0 + quad*4 + r;
            if (row < N) Y[(size_t)row*128 + nt*16 + lq] = f2b(acc[nt][r] + bias[nt]);
          }
      }
    }
  } else {
    int b = bid - ngemm;
    int* cnt  = (int*)smem;
    int* offl = cnt + NPB;
    int* s1   = offl + NPB + 1;
    int* win  = s1 + 256;
    int node0 = b * NPB;
    int base  = b * SLOTS;
    int ce = bucketCnt[b]; if (ce > SLOTS) ce = SLOTS;
    for (int i=t;i<NPB;i+=256) cnt[i]=0;
    __syncthreads();
    for (int i=t;i<ce;i+=256) atomicAdd(&cnt[pairD[(size_t)base+i]-node0], 1);
    __syncthreads();
    int a0 = cnt[2*t], a1 = cnt[2*t+1];
    s1[t] = a0 + a1;
    __syncthreads();
    for (int st=1; st<256; st<<=1){
      int v = (t>=st)? s1[t-st] : 0;
      __syncthreads();
      s1[t] += v;
      __syncthreads();
    }
    int excl = (t>0)? s1[t-1] : 0;
    offl[2*t] = excl; offl[2*t+1] = excl + a0;
    __syncthreads();
    for (int i=t;i<NPB;i+=256){
      int node = node0 + i;
      if (node < N){ off[node] = base + offl[i]; deg[node] = cnt[i]; }
    }
    __syncthreads();
    if (ce <= CAP){
      for (int i=t;i<ce;i+=256){
        int d = pairD[(size_t)base+i];
        int p = atomicAdd(&offl[d-node0], 1);
        win[p] = pairS[(size_t)base+i];
      }
      __syncthreads();
      for (int i=t;i<ce;i+=256) adj[(size_t)base+i] = win[i];
    } else {
      for (int i=t;i<ce;i+=256){
        int d = pairD[(size_t)base+i];
        int p = atomicAdd(&offl[d-node0], 1);
        adj[(size_t)base+p] = pairS[(size_t)base+i];
      }
    }
  }
}

// ================= combine0: 16 nodes/block, LDS adj window, 4-node interleave ===========
__global__ __launch_bounds__(256) void combine0_f8(
    const unsigned char* __restrict__ agg8, const ushort* __restrict__ rootsrc,
    const ushort* __restrict__ ressrc, const float* __restrict__ bias,
    const int* __restrict__ off, const int* __restrict__ deg,
    const int* __restrict__ adj, ushort* __restrict__ out, int n)
{
  __shared__ int adjl[1024];
  int t = threadIdx.x, w = t>>6, lane = t&63;
  int node0 = blockIdx.x*16;
  int nlast = node0+15 < n-1 ? node0+15 : n-1;
  int e0 = off[node0];
  int eTot = off[nlast] + deg[nlast] - e0;
  bool ovf = (eTot > 1024);
  if (!ovf){
    for (int i=t; i<eTot; i+=256) adjl[i] = adj[e0+i];
  }
  __syncthreads();
  const int* ap = ovf ? (adj + e0) : (const int*)adjl;
  const ushort* a8 = (const ushort*)agg8;

  int sl[4], dgv[4];
  float a0[4] = {0.f,0.f,0.f,0.f}, a1[4] = {0.f,0.f,0.f,0.f};
  int maxd = 0;
  #pragma unroll
  for (int j=0;j<4;j++){
    int node = node0 + w*4 + j;
    bool ok = node < n;
    sl[j]  = ok ? off[node] - e0 : 0;
    dgv[j] = ok ? deg[node] : 0;
    if (dgv[j] > maxd) maxd = dgv[j];
  }
  for (int c=0; c<maxd; c+=16){
    ushort u[4][16];
    #pragma unroll
    for (int j=0;j<4;j++){
      int lim = dgv[j] - c;
      #pragma unroll
      for (int jj=0;jj<16;jj++)
        if (jj < lim) u[j][jj] = a8[(size_t)ap[sl[j]+c+jj]*64 + lane];
    }
    #pragma unroll
    for (int j=0;j<4;j++){
      int lim = dgv[j] - c;
      #pragma unroll
      for (int jj=0;jj<16;jj++)
        if (jj < lim){ float2v f = dec8(u[j][jj]); a0[j] += f[0]; a1[j] += f[1]; }
    }
  }
  #pragma unroll
  for (int j=0;j<4;j++){
    int node = node0 + w*4 + j;
    if (node >= n) continue;
    int cnt = dgv[j];
    float inv = 1.f / (float)((cnt > 1)? cnt : 1);
    unsigned rt = ((const unsigned*)rootsrc)[(size_t)node*64 + lane];
    unsigned rs = ((const unsigned*)ressrc)[(size_t)node*64 + lane];
    float o0 = fmaxf(a0[j]*inv + bias[2*lane]   + blo(rt), 0.f) + blo(rs);
    float o1 = fmaxf(a1[j]*inv + bias[2*lane+1] + bhi(rt), 0.f) + bhi(rs);
    ((unsigned*)out)[(size_t)node*64 + lane] = (unsigned)f2b(o0) | ((unsigned)f2b(o1) << 16);
  }
}

// ================= combine1 + head: LDS adj window, 4-node interleave, MFMA head ==========
__global__ __launch_bounds__(256) void combine1_head(
    const unsigned char* __restrict__ agg8, const ushort* __restrict__ hr1,
    const ushort* __restrict__ h, const float* __restrict__ bl1,
    const int* __restrict__ off, const int* __restrict__ deg, const int* __restrict__ adj,
    const ushort* __restrict__ W1f, const float* __restrict__ b1,
    const float* __restrict__ W2, const float* __restrict__ b2,
    const float* __restrict__ alogit, const float* __restrict__ rer,
    float* __restrict__ out, int n)
{
  __shared__ __align__(16) ushort W1s[8192];
  __shared__ __align__(16) ushort h2s[16*136];
  __shared__ int adjl[1024];
  int t = threadIdx.x, w = t>>6, lane = t&63, lq = lane&15, quad = lane>>4;
  #pragma unroll
  for (int j=0;j<4;j++){
    int g = w + j*4;
    glds16(W1f + (size_t)g*512 + lane*8, W1s + g*512);
  }
  int node0 = blockIdx.x*16;
  int nlast = node0+15 < n-1 ? node0+15 : n-1;
  int e0 = off[node0];
  int eTot = off[nlast] + deg[nlast] - e0;
  bool ovf = (eTot > 1024);
  if (!ovf){
    for (int i=t; i<eTot; i+=256) adjl[i] = adj[e0+i];
  }
  __syncthreads();   // drains glds (W1s) + adjl writes
  const int* ap = ovf ? (adj + e0) : (const int*)adjl;
  const ushort* a8 = (const ushort*)agg8;
  unsigned* h2u = (unsigned*)h2s;

  int sl[4], dgv[4];
  float a0[4] = {0.f,0.f,0.f,0.f}, a1[4] = {0.f,0.f,0.f,0.f};
  int maxd = 0;
  #pragma unroll
  for (int j=0;j<4;j++){
    int node = node0 + w*4 + j;
    bool ok = node < n;
    sl[j]  = ok ? off[node] - e0 : 0;
    dgv[j] = ok ? deg[node] : 0;
    if (dgv[j] > maxd) maxd = dgv[j];
  }
  for (int c=0; c<maxd; c+=16){
    ushort u[4][16];
    #pragma unroll
    for (int j=0;j<4;j++){
      int lim = dgv[j] - c;
      #pragma unroll
      for (int jj=0;jj<16;jj++)
        if (jj < lim) u[j][jj] = a8[(size_t)ap[sl[j]+c+jj]*64 + lane];
    }
    #pragma unroll
    for (int j=0;j<4;j++){
      int lim = dgv[j] - c;
      #pragma unroll
      for (int jj=0;jj<16;jj++)
        if (jj < lim){ float2v f = dec8(u[j][jj]); a0[j] += f[0]; a1[j] += f[1]; }
    }
  }
  #pragma unroll
  for (int j=0;j<4;j++){
    int node = node0 + w*4 + j;
    float o0 = 0.f, o1 = 0.f;
    if (node < n){
      int cnt = dgv[j];
      float inv = 1.f / (float)((cnt > 1)? cnt : 1);
      unsigned rt = ((const unsigned*)hr1)[(size_t)node*64 + lane];
      unsigned rs = ((const unsigned*)h)[(size_t)node*64 + lane];
      o0 = fmaxf(a0[j]*inv + bl1[2*lane]   + blo(rt), 0.f) + blo(rs);
      o1 = fmaxf(a1[j]*inv + bl1[2*lane+1] + bhi(rt), 0.f) + bhi(rs);
    }
    h2u[(w*4+j)*68 + lane] = (unsigned)f2b(o0) | ((unsigned)f2b(o1) << 16);
  }
  __syncthreads();

  short8 av[4];
  #pragma unroll
  for (int ks=0;ks<4;ks++)
    av[ks] = *(const short8*)(h2s + lq*136 + ks*32 + quad*8);
  float4v acc[4];
  #pragma unroll
  for (int nt=0;nt<4;nt++)
    #pragma unroll
    for (int r=0;r<4;r++) acc[nt][r] = 0.f;
  #pragma unroll
  for (int ks=0;ks<4;ks++){
    #pragma unroll
    for (int nt=0;nt<4;nt++){
      short8 bf = *(const short8*)(W1s + ((ks*4 + nt)*64 + lane)*8);
      acc[nt] = __builtin_amdgcn_mfma_f32_16x16x32_bf16(av[ks], bf, acc[nt], 0,0,0);
    }
  }
  float al = alogit[0];
  float a  = 1.f / (1.f + __expf(-al));
  float pw[4] = {0.f,0.f,0.f,0.f};
  #pragma unroll
  for (int nt=0; nt<4; nt++){
    int c = nt*16 + lq;
    float w2 = W2[c];
    float bb = b1[c];
    #pragma unroll
    for (int r=0; r<4; r++)
      pw[r] += fmaxf(acc[nt][r] + bb, 0.f) * w2;
  }
  #pragma unroll
  for (int mask=1; mask<16; mask<<=1){
    #pragma unroll
    for (int r=0; r<4; r++)
      pw[r] += __shfl_xor(pw[r], mask);
  }
  if (lq == 0){
    #pragma unroll
    for (int r=0; r<4; r++){
      int rl = quad*4 + r;
      if ((rl >> 2) == w){
        int node = node0 + rl;
        if (node < n)
          out[node] = a * rer[node] + (1.f - a) * (pw[r] + b2[0]);
      }
    }
  }
}

// ================= GEMM1: weights-resident; hl1 output fp8, hr1 bf16 =================
__global__ __launch_bounds__(256) void gemm1_wres(
    const ushort* __restrict__ h, int N,
    const ushort* __restrict__ Wl1f, const ushort* __restrict__ Wr1f,
    unsigned char* __restrict__ q8, ushort* __restrict__ hr1)
{
  __shared__ __align__(16) ushort Bs[32768];
  int t = threadIdx.x, w = t>>6, lane = t&63, lq = lane&15, quad = lane>>4;
  int tile = blockIdx.x;
  #pragma unroll
  for (int j=0;j<16;j++){
    int r = w + j*4;
    int m = r>>5, g = r&31;
    const ushort* Wm = m ? Wr1f : Wl1f;
    glds16(Wm + (size_t)g*512 + lane*8, Bs + r*512);
  }
  short8 av[2][4];
  int row0 = tile*128 + w*32;
  #pragma unroll
  for (int mt=0;mt<2;mt++){
    int row = row0 + mt*16 + lq; if (row >= N) row = N-1;
    #pragma unroll
    for (int ks=0;ks<4;ks++)
      av[mt][ks] = *(const short8*)(h + (size_t)row*128 + ks*32 + quad*8);
  }
  __syncthreads();
  #pragma unroll
  for (int m=0;m<2;m++){
    float4v acc[2][8];
    #pragma unroll
    for (int i=0;i<2;i++)
      #pragma unroll
      for (int j=0;j<8;j++)
        #pragma unroll
        for (int r=0;r<4;r++) acc[i][j][r] = 0.f;
    #pragma unroll
    for (int ks=0;ks<4;ks++){
      #pragma unroll
      for (int nt=0;nt<8;nt++){
        short8 bf = *(const short8*)(Bs + ((m*32 + ks*8 + nt)*64 + lane)*8);
        acc[0][nt] = __builtin_amdgcn_mfma_f32_16x16x32_bf16(av[0][ks], bf, acc[0][nt], 0,0,0);
        acc[1][nt] = __builtin_amdgcn_mfma_f32_16x16x32_bf16(av[1][ks], bf, acc[1][nt], 0,0,0);
      }
    }
    #pragma unroll
    for (int mt=0;mt<2;mt++){
      #pragma unroll
      for (int r=0;r<4;r++){
        int row = row0 + mt*16 + quad*4 + r;
        if (row < N){
          if (m == 0){
            #pragma unroll
            for (int nt=0;nt<8;nt++)
              q8[(size_t)row*128 + nt*16 + lq] = enc8(acc[mt][nt][r]);
          } else {
            #pragma unroll
            for (int nt=0;nt<8;nt++)
              hr1[(size_t)row*128 + nt*16 + lq] = f2b(acc[mt][nt][r]);
          }
        }
      }
    }
  }
}

extern "C" void kernel_launch(void* const* d_in, const int* in_sizes, int n_in,
                              void* d_out, int out_size, void* d_ws, size_t ws_size,
                              hipStream_t stream)
{
  (void)n_in; (void)out_size; (void)ws_size;
  const float* x    = (const float*)d_in[0];
  const int*   ei   = (const int*)d_in[1];
  const float* rer  = (const float*)d_in[2];
  const float* Wp   = (const float*)d_in[3];
  const float* bp   = (const float*)d_in[4];
  const float* Wl0  = (const float*)d_in[5];
  const float* bl0  = (const float*)d_in[6];
  const float* Wr0  = (const float*)d_in[7];
  const float* Wl1  = (const float*)d_in[8];
  const float* bl1  = (const float*)d_in[9];
  const float* Wr1  = (const float*)d_in[10];
  const float* W1   = (const float*)d_in[11];
  const float* b1   = (const float*)d_in[12];
  const float* W2   = (const float*)d_in[13];
  const float* b2   = (const float*)d_in[14];
  const float* alogit = (const float*)d_in[15];

  const int N = in_sizes[2];      // 50000
  const int E = in_sizes[1] / 2;  // 800000
  const int* src = ei;
  const int* dst = ei + E;
  const int NB = (N + NPB - 1) / NPB;        // 98
  const int nstripe = (N + 15) / 16;         // 3125
  const int ntile = (N + 127) / 128;         // 391
  const int nPart = (E + EPB - 1) / EPB;     // 391
  const int nConv = (nstripe*512 + 255)/256; // 6250

  // workspace layout
  ushort* U = (ushort*)d_ws;
  ushort* xb  = U;                           // stripe-frag x
  ushort* xp  = xb + (size_t)nstripe*512*8;  // [N][128] residual
  ushort* xr0 = xp  + (size_t)N*DH;          // root0; reused as hr1
  ushort* h   = xr0 + (size_t)N*DH;
  unsigned char* q8 = (unsigned char*)(h + (size_t)N*DH);  // [N][128] fp8 (xl0 then hl1)
  ushort* Wpf  = (ushort*)(q8 + (size_t)N*DH);
  ushort* Wl0f = Wpf  + (size_t)4096*8;
  ushort* Wr0f = Wl0f + (size_t)4096*8;
  ushort* Wl1f = Wr0f + (size_t)4096*8;
  ushort* Wr1f = Wl1f + (size_t)2048*8;
  ushort* W1f  = Wr1f + (size_t)2048*8;
  int* I = (int*)(W1f + (size_t)1024*8);
  int* bucketCnt = I;
  int* off   = bucketCnt + NBMAX;
  int* deg   = off + N;
  int* pairS = deg + N;
  int* pairD = pairS + (size_t)NB*SLOTS;
  int* adj   = pairD + (size_t)NB*SLOTS;

  hipMemsetAsync(bucketCnt, 0, NBMAX*sizeof(int), stream);

  // L1: [partition | convert | prep]
  fused_front<<<nPart + nConv + 68, 256, 0, stream>>>(
      x, N, xb, nstripe, Wp, Wl0, Wr0, Wl1, Wr1, W1,
      Wpf, Wl0f, Wr0f, Wl1f, Wr1f, W1f,
      src, dst, E, NB, bucketCnt, pairS, pairD, nPart, nConv);

  // L2: [GEMM0 | bucket_csr]  (xl0 -> q8 fp8)
  gemm0_csr<<<768 + NB, 256, 0, stream>>>(
      xb, N, nstripe, 768, Wpf, Wl0f, Wr0f, bp, xp, q8, xr0,
      bucketCnt, pairS, pairD, off, deg, adj);

  // combine0: h = relu(mean_fp8(q8[nbrs]) + bl0 + xr0) + xp
  combine0_f8<<<(N+15)/16, 256, 0, stream>>>(q8, xr0, xp, bl0, off, deg, adj, h, N);

  // GEMM1: hl1 -> q8 (fp8), hr1 -> xr0 (bf16)
  gemm1_wres<<<ntile, 256, 0, stream>>>(h, N, Wl1f, Wr1f, q8, xr0);

  // combine1+head fused
  combine1_head<<<(N+15)/16, 256, 0, stream>>>(
      q8, xr0, h, bl1, off, deg, adj, W1f, b1, W2, b2, alogit, rer, (float*)d_out, N);
}